// Round 7
// baseline (464.441 us; speedup 1.0000x reference)
//
#include <hip/hip_runtime.h>
#include <math.h>

// Problem constants (fixed by the reference)
constexpr int CB = 2, CS = 2048, CD = 1024, CH = 16, CHD = 64;
constexpr int CEMB = 1024;

typedef unsigned short ushort_t;
typedef __attribute__((ext_vector_type(8))) short short8;   // 8 bf16 = 4 VGPR
typedef __attribute__((ext_vector_type(4))) float f32x4;    // MFMA acc

// fp32 -> bf16 round-to-nearest-even (finite data only)
__device__ __forceinline__ ushort_t f2bf(float x) {
    unsigned int u = __builtin_bit_cast(unsigned int, x);
    u = u + 0x7fffu + ((u >> 16) & 1u);
    return (ushort_t)(u >> 16);
}
__device__ __forceinline__ float bf2f(ushort_t h) {
    unsigned int u = ((unsigned int)h) << 16;
    return __builtin_bit_cast(float, u);
}

// ===========================================================================
// Weight pre-pass: W[k][n] fp32 -> WT_hi[n][k], WT_lo[n][k] bf16 (split).
// ===========================================================================
__global__ __launch_bounds__(256) void convert_wt(
    const float* __restrict__ W0, const float* __restrict__ W1,
    const float* __restrict__ W2, const float* __restrict__ W3,
    ushort_t* __restrict__ H0, ushort_t* __restrict__ L0,
    ushort_t* __restrict__ H1, ushort_t* __restrict__ L1,
    ushort_t* __restrict__ H2, ushort_t* __restrict__ L2,
    ushort_t* __restrict__ H3, ushort_t* __restrict__ L3) {
    const float* W;
    ushort_t* Hd;
    ushort_t* Ld;
    switch (blockIdx.z) {
        case 0: W = W0; Hd = H0; Ld = L0; break;
        case 1: W = W1; Hd = H1; Ld = L1; break;
        case 2: W = W2; Hd = H2; Ld = L2; break;
        default: W = W3; Hd = H3; Ld = L3; break;
    }
    const int n0 = blockIdx.x * 64, k0 = blockIdx.y * 64;
    __shared__ float Ls[64][65];
    const int t = threadIdx.x;
#pragma unroll
    for (int rep = 0; rep < 4; rep++) {
        const int r = rep * 16 + (t >> 4);
        const int c4 = (t & 15) * 4;
        *(float4*)&Ls[r][c4] = *(const float4*)&W[(size_t)(k0 + r) * CEMB + n0 + c4];
    }
    __syncthreads();
    const int n = t >> 2, kc = (t & 3) * 16;
#pragma unroll
    for (int c = 0; c < 2; c++) {
        union { ushort_t us[8]; uint4 v; } H, L;
#pragma unroll
        for (int j = 0; j < 8; j++) {
            const float x = Ls[kc + c * 8 + j][n];
            const ushort_t h = f2bf(x);
            H.us[j] = h;
            L.us[j] = f2bf(x - bf2f(h));
        }
        const size_t dst = (size_t)(n0 + n) * CEMB + k0 + kc + c * 8;
        *(uint4*)&Hd[dst] = H.v;
        *(uint4*)&Ld[dst] = L.v;
    }
}

// ===========================================================================
// Split-bf16 MFMA GEMM: 128x128 tile, BK=32, 4 waves, 4x4 16x16x32 frags.
// Epilogue modes: 0 = fp32 row-major [M][N]
//                 1 = split bf16 scatter [b,h,s,d], pre-scaled
//                 2 = bf16 [b,h,d,s] via per-wave LDS transpose (coalesced)
// ===========================================================================
constexpr int LP = 72;  // LDS pitch in bf16 elems (144B = 9 quads, odd)

template <bool GATHER_A>
__device__ __forceinline__ void gemm_split_body(
    const float* __restrict__ A, const ushort_t* __restrict__ Bhi,
    const ushort_t* __restrict__ Blo, float* __restrict__ Cf,
    ushort_t* __restrict__ C0, ushort_t* __restrict__ C1, float scale,
    int emode, int M, int N, int K) {
    __shared__ char gpool[36864];  // staging 32KB; emode2 transpose 36KB
    ushort_t* const As_hi = (ushort_t*)gpool;
    ushort_t* const As_lo = As_hi + 128 * 32;
    ushort_t* const Bs_hi = As_lo + 128 * 32;
    ushort_t* const Bs_lo = Bs_hi + 128 * 32;
    const int tid = threadIdx.x;
    const int row0 = blockIdx.y * 128, col0 = blockIdx.x * 128;
    const int w = tid >> 6, l = tid & 63, lr = l & 15, lg = l >> 4;
    const int wm = w >> 1, wn = w & 1;

    f32x4 acc[4][4];
#pragma unroll
    for (int i = 0; i < 4; i++)
#pragma unroll
        for (int j = 0; j < 4; j++) acc[i][j] = (f32x4)(0.f);

    const int st_r = tid >> 1;
    const int st_kh = (tid & 1) * 16;

    for (int k0 = 0; k0 < K; k0 += 32) {
        {   // stage A: fp32 -> split bf16
            const int gm = row0 + st_r;
            const int gk = k0 + st_kh;
            const float* src;
            if (GATHER_A) {
                const int b_ = gm >> 11, s_ = gm & 2047;
                const int h_ = gk >> 6, d_ = gk & 63;
                src = &A[(((size_t)b_ * CH + h_) * CS + s_) * CHD + d_];
            } else {
                src = &A[(size_t)gm * K + gk];
            }
            float va[16];
#pragma unroll
            for (int r = 0; r < 4; r++)
                *(float4*)&va[r * 4] = *(const float4*)&src[r * 4];
#pragma unroll
            for (int c = 0; c < 2; c++) {
                union { ushort_t us[8]; uint4 v; } H, L;
#pragma unroll
                for (int j = 0; j < 8; j++) {
                    const float x = va[c * 8 + j];
                    const ushort_t h = f2bf(x);
                    H.us[j] = h;
                    L.us[j] = f2bf(x - bf2f(h));
                }
                const int chunk = (st_kh >> 3) + c;
                const int csw = chunk ^ ((st_r >> 1) & 3);
                *(uint4*)&As_hi[st_r * 32 + csw * 8] = H.v;
                *(uint4*)&As_lo[st_r * 32 + csw * 8] = L.v;
            }
        }
        {   // stage B: pre-split bf16 [n][k]
            const size_t base = (size_t)(col0 + st_r) * K + k0 + st_kh;
#pragma unroll
            for (int c = 0; c < 2; c++) {
                const uint4 hv = *(const uint4*)&Bhi[base + c * 8];
                const uint4 lv = *(const uint4*)&Blo[base + c * 8];
                const int chunk = (st_kh >> 3) + c;
                const int csw = chunk ^ ((st_r >> 1) & 3);
                *(uint4*)&Bs_hi[st_r * 32 + csw * 8] = hv;
                *(uint4*)&Bs_lo[st_r * 32 + csw * 8] = lv;
            }
        }
        __syncthreads();

        short8 ah[4], al[4], bh[4], bl[4];
#pragma unroll
        for (int i = 0; i < 4; i++) {
            const int r = wm * 64 + i * 16 + lr;
            const int cs = lg ^ ((r >> 1) & 3);
            ah[i] = *(const short8*)&As_hi[r * 32 + cs * 8];
            al[i] = *(const short8*)&As_lo[r * 32 + cs * 8];
        }
#pragma unroll
        for (int j = 0; j < 4; j++) {
            const int cc = wn * 64 + j * 16 + lr;
            const int cs = lg ^ ((cc >> 1) & 3);
            bh[j] = *(const short8*)&Bs_hi[cc * 32 + cs * 8];
            bl[j] = *(const short8*)&Bs_lo[cc * 32 + cs * 8];
        }
#pragma unroll
        for (int j = 0; j < 4; j++)
#pragma unroll
            for (int i = 0; i < 4; i++) {
                acc[i][j] = __builtin_amdgcn_mfma_f32_16x16x32_bf16(
                    al[i], bh[j], acc[i][j], 0, 0, 0);
                acc[i][j] = __builtin_amdgcn_mfma_f32_16x16x32_bf16(
                    ah[i], bl[j], acc[i][j], 0, 0, 0);
                acc[i][j] = __builtin_amdgcn_mfma_f32_16x16x32_bf16(
                    ah[i], bh[j], acc[i][j], 0, 0, 0);
            }
        __syncthreads();
    }

    if (emode == 2) {
        // Vt [b,h,d,s]: per-wave 64x64 transpose through LDS, uint4 stores
        // of 8 consecutive s (128B runs). Wave-private region, no barrier.
        ushort_t* const T = (ushort_t*)gpool + w * 64 * LP;
#pragma unroll
        for (int i = 0; i < 4; i++)
#pragma unroll
            for (int j = 0; j < 4; j++) {
                const unsigned int a =
                    (unsigned int)f2bf(acc[i][j][0]) |
                    ((unsigned int)f2bf(acc[i][j][1]) << 16);
                const unsigned int b =
                    (unsigned int)f2bf(acc[i][j][2]) |
                    ((unsigned int)f2bf(acc[i][j][3]) << 16);
                *(uint2*)&T[(j * 16 + lr) * LP + i * 16 + 4 * lg] =
                    make_uint2(a, b);
            }
#pragma unroll
        for (int grp = 0; grp < 8; grp++) {
            const int dl = (l >> 3) + grp * 8;
            const int s8 = (l & 7) * 8;
            const uint4 vv = *(const uint4*)&T[dl * LP + s8];
            const int gm = row0 + wm * 64 + s8;
            const int b_ = gm >> 11, ss = gm & 2047;
            const int dg = col0 + wn * 64 + dl;
            const int h_ = dg >> 6, hd = dg & 63;
            *(uint4*)&C0[(((size_t)b_ * CH + h_) * CHD + hd) * CS + ss] = vv;
        }
        return;
    }

#pragma unroll
    for (int i = 0; i < 4; i++)
#pragma unroll
        for (int j = 0; j < 4; j++) {
            const int cc = col0 + wn * 64 + j * 16 + lr;
#pragma unroll
            for (int r = 0; r < 4; r++) {
                const int cr = row0 + wm * 64 + i * 16 + lg * 4 + r;
                const float vv = acc[i][j][r];
                if (emode == 0) {
                    Cf[(size_t)cr * N + cc] = vv;
                } else {  // emode 1: split bf16 scatter [b,h,s,d]
                    const int b_ = cr >> 11, s_ = cr & 2047;
                    const int h_ = cc >> 6, d_ = cc & 63;
                    const size_t idx =
                        (((size_t)b_ * CH + h_) * CS + s_) * CHD + d_;
                    const float x = vv * scale;
                    const ushort_t hb = f2bf(x);
                    C0[idx] = hb;
                    C1[idx] = f2bf(x - bf2f(hb));
                }
            }
        }
}

__global__ __launch_bounds__(256, 2) void qkv_proj(
    const float* __restrict__ q, const float* __restrict__ k,
    const float* __restrict__ v,
    const ushort_t* __restrict__ hq, const ushort_t* __restrict__ lq,
    const ushort_t* __restrict__ hk, const ushort_t* __restrict__ lk,
    const ushort_t* __restrict__ hv, const ushort_t* __restrict__ lv,
    ushort_t* __restrict__ Qhi, ushort_t* __restrict__ Qlo,
    ushort_t* __restrict__ Khi, ushort_t* __restrict__ Klo,
    ushort_t* __restrict__ Vt) {
    const float* A;
    const ushort_t* Bh;
    const ushort_t* Bl;
    ushort_t* C0;
    ushort_t* C1 = nullptr;
    float scale = 1.0f;
    int emode;
    if (blockIdx.z == 0) {
        A = q; Bh = hq; Bl = lq; C0 = Qhi; C1 = Qlo; scale = 0.125f; emode = 1;
    } else if (blockIdx.z == 1) {
        A = k; Bh = hk; Bl = lk; C0 = Khi; C1 = Klo; emode = 1;
    } else {
        A = v; Bh = hv; Bl = lv; C0 = Vt; emode = 2;
    }
    gemm_split_body<false>(A, Bh, Bl, nullptr, C0, C1, scale, emode,
                           CB * CS, CEMB, CD);
}

__global__ __launch_bounds__(256, 2) void out_proj(
    const float* __restrict__ attn, const ushort_t* __restrict__ ho,
    const ushort_t* __restrict__ lo_, float* __restrict__ out) {
    gemm_split_body<true>(attn, ho, lo_, out, nullptr, nullptr, 1.0f, 0,
                          CB * CS, CEMB, CEMB);
}

// ===========================================================================
// MFMA flash attention, swapped operands, ONE q-tile per block.
// Grid 1024 (= 32 q-tiles x 32 bh), 4 waves x 16 q-rows each -> all waves
// active every iteration (no causal pairing idle). 4 blocks/CU. XCD swizzle:
// each XCD gets 4 consecutive bh (K/V set 3MB < 4MB L2), longest tile first.
// S^T = mfma(K,Q): lane owns one q-row; softmax = in-reg + 2 shuffles.
// O epilogue: per-wave LDS transpose -> coalesced float4 stores.
// ===========================================================================
__global__ __launch_bounds__(256, 4) void flash_mfma(
    const ushort_t* __restrict__ Qhi, const ushort_t* __restrict__ Qlo,
    const ushort_t* __restrict__ Khi, const ushort_t* __restrict__ Klo,
    const ushort_t* __restrict__ Vt, float* __restrict__ O,
    const int* __restrict__ maskedp) {
    __shared__ char pool_raw[36864];
    ushort_t* const Ks_hi = (ushort_t*)pool_raw;         // 64*LP
    ushort_t* const Ks_lo = Ks_hi + 64 * LP;             // 64*LP
    ushort_t* const Vs = Ks_lo + 64 * LP;                // 64*LP
    ushort_t* const PsA = Vs + 64 * LP;                  // 4 * 16*LP

    const int tid = threadIdx.x;
    const int w = tid >> 6, l = tid & 63, lr = l & 15, lg = l >> 4;
    const int masked = maskedp[0];
    const int id = blockIdx.x;
    const int sid = (id & 7) * 128 + (id >> 3);  // XCD-contiguous chunks
    const int bh = sid >> 5;
    const int qt = 31 - (sid & 31);              // longest first per chunk
    const int q0 = qt * 64 + w * 16;
    const size_t bhoff = (size_t)bh * CS * CHD;
    ushort_t* const Ps = PsA + w * 16 * LP;

    // Q fragments (B-operand): row q0+lr, d = ds*32 + lg*8 .. +8
    short8 qh[2], ql[2];
#pragma unroll
    for (int ds = 0; ds < 2; ds++) {
        const size_t off = bhoff + (size_t)(q0 + lr) * CHD + ds * 32 + lg * 8;
        qh[ds] = *(const short8*)&Qhi[off];
        ql[ds] = *(const short8*)&Qlo[off];
    }

    f32x4 Oacc[4];
    float m_i = -INFINITY, l_i = 0.f;
#pragma unroll
    for (int df = 0; df < 4; df++) Oacc[df] = (f32x4)(0.f);

    const int tmax = masked ? qt : 31;
    const int st_r = tid >> 2;
    const int st_c = tid & 3;

    // prefetch tile 0
    uint4 pk_hi[2], pk_lo[2], pv[2];
#pragma unroll
    for (int p = 0; p < 2; p++) {
        const int c = st_c + p * 4;
        const size_t kgl = bhoff + (size_t)st_r * CHD + c * 8;
        pk_hi[p] = *(const uint4*)&Khi[kgl];
        pk_lo[p] = *(const uint4*)&Klo[kgl];
        const size_t vgl = ((size_t)bh * CHD + st_r) * CS + c * 8;
        pv[p] = *(const uint4*)&Vt[vgl];
    }

    for (int t = 0; t <= tmax; t++) {
#pragma unroll
        for (int p = 0; p < 2; p++) {
            const int c = st_c + p * 4;
            *(uint4*)&Ks_hi[st_r * LP + c * 8] = pk_hi[p];
            *(uint4*)&Ks_lo[st_r * LP + c * 8] = pk_lo[p];
            *(uint4*)&Vs[st_r * LP + c * 8] = pv[p];
        }
        __syncthreads();

        if (t < tmax) {
#pragma unroll
            for (int p = 0; p < 2; p++) {
                const int c = st_c + p * 4;
                const size_t kgl =
                    bhoff + (size_t)((t + 1) * 64 + st_r) * CHD + c * 8;
                pk_hi[p] = *(const uint4*)&Khi[kgl];
                pk_lo[p] = *(const uint4*)&Klo[kgl];
                const size_t vgl =
                    ((size_t)bh * CHD + st_r) * CS + (t + 1) * 64 + c * 8;
                pv[p] = *(const uint4*)&Vt[vgl];
            }
        }

        // ---- S^T = K @ Q^T (split: Kh*Ql + Kl*Qh + Kh*Qh) ----
        f32x4 S[4];
#pragma unroll
        for (int kf = 0; kf < 4; kf++) S[kf] = (f32x4)(0.f);
#pragma unroll
        for (int ds = 0; ds < 2; ds++) {
            short8 kh[4], kl[4];
#pragma unroll
            for (int kf = 0; kf < 4; kf++) {
                const int off = (kf * 16 + lr) * LP + ds * 32 + lg * 8;
                kh[kf] = *(const short8*)&Ks_hi[off];
                kl[kf] = *(const short8*)&Ks_lo[off];
            }
#pragma unroll
            for (int kf = 0; kf < 4; kf++) {
                S[kf] = __builtin_amdgcn_mfma_f32_16x16x32_bf16(
                    kh[kf], ql[ds], S[kf], 0, 0, 0);
                S[kf] = __builtin_amdgcn_mfma_f32_16x16x32_bf16(
                    kl[kf], qh[ds], S[kf], 0, 0, 0);
                S[kf] = __builtin_amdgcn_mfma_f32_16x16x32_bf16(
                    kh[kf], qh[ds], S[kf], 0, 0, 0);
            }
        }

        // ---- causal mask (diagonal tile only; same qt for all waves) ----
        if (masked && t == qt) {
            const int qg = q0 + lr;
#pragma unroll
            for (int kf = 0; kf < 4; kf++)
#pragma unroll
                for (int r = 0; r < 4; r++) {
                    const int kg = t * 64 + kf * 16 + 4 * lg + r;
                    if (kg > qg) S[kf][r] = -INFINITY;
                }
        }

        // ---- online softmax: in-reg over 16 + 2 shuffles across lg ----
        {
            float mt = -INFINITY;
#pragma unroll
            for (int kf = 0; kf < 4; kf++)
#pragma unroll
                for (int r = 0; r < 4; r++) mt = fmaxf(mt, S[kf][r]);
            mt = fmaxf(mt, __shfl_xor(mt, 16));
            mt = fmaxf(mt, __shfl_xor(mt, 32));
            const float mn = fmaxf(m_i, mt);
            const float corr = __expf(m_i - mn);
            float rs = 0.f;
#pragma unroll
            for (int kf = 0; kf < 4; kf++)
#pragma unroll
                for (int r = 0; r < 4; r++) {
                    const float p = __expf(S[kf][r] - mn);
                    S[kf][r] = p;
                    rs += p;
                }
            rs += __shfl_xor(rs, 16);
            rs += __shfl_xor(rs, 32);
            l_i = l_i * corr + rs;
            m_i = mn;
#pragma unroll
            for (int df = 0; df < 4; df++) Oacc[df] *= corr;
        }

        // ---- pack P: same-lane regs -> one b64 write per kf ----
#pragma unroll
        for (int kf = 0; kf < 4; kf++) {
            const unsigned int a = (unsigned int)f2bf(S[kf][0]) |
                                   ((unsigned int)f2bf(S[kf][1]) << 16);
            const unsigned int b = (unsigned int)f2bf(S[kf][2]) |
                                   ((unsigned int)f2bf(S[kf][3]) << 16);
            *(uint2*)&Ps[lr * LP + kf * 16 + 4 * lg] = make_uint2(a, b);
        }

        // ---- O^T += V^T @ P^T (per-wave private P, no barrier) ----
#pragma unroll
        for (int ks = 0; ks < 2; ks++) {
            short8 vb[4];
#pragma unroll
            for (int df = 0; df < 4; df++)
                vb[df] = *(const short8*)&Vs[(df * 16 + lr) * LP + ks * 32 +
                                             lg * 8];
            const short8 pb =
                *(const short8*)&Ps[lr * LP + ks * 32 + lg * 8];
#pragma unroll
            for (int df = 0; df < 4; df++)
                Oacc[df] = __builtin_amdgcn_mfma_f32_16x16x32_bf16(
                    vb[df], pb, Oacc[df], 0, 0, 0);
        }
        __syncthreads();  // protect K/V LDS for next tile
    }

    // ---- epilogue: normalize, per-wave LDS transpose, coalesced stores ----
    float* const T = (float*)pool_raw + (size_t)w * 16 * LP;
    const float inv = 1.0f / l_i;
#pragma unroll
    for (int df = 0; df < 4; df++) {
        f32x4 vv = Oacc[df] * inv;
        *(f32x4*)&T[lr * LP + df * 16 + 4 * lg] = vv;
    }
#pragma unroll
    for (int grp = 0; grp < 4; grp++) {
        const int qrow = grp * 4 + lg;
        const float4 vv = *(const float4*)&T[qrow * LP + lr * 4];
        *(float4*)&O[bhoff + (size_t)(q0 + qrow) * CHD + lr * 4] = vv;
    }
}

// ===========================================================================
extern "C" void kernel_launch(void* const* d_in, const int* in_sizes, int n_in,
                              void* d_out, int out_size, void* d_ws,
                              size_t ws_size, hipStream_t stream) {
    const float* q  = (const float*)d_in[0];
    const float* k  = (const float*)d_in[1];
    const float* v  = (const float*)d_in[2];
    const float* Wq = (const float*)d_in[3];
    const float* Wk = (const float*)d_in[4];
    const float* Wv = (const float*)d_in[5];
    const float* Wo = (const float*)d_in[6];
    const int* masked = (const int*)d_in[7];

    float* out  = (float*)d_out;                 // [B,S,1024]
    float* attn = out + (size_t)CB * CS * CEMB;  // [B,H,S,64] (2nd output)

    // workspace layout (bf16 buffers, all 16B aligned):
    const size_t NE = (size_t)CB * CS * CEMB;  // 4M elems per tensor
    ushort_t* wsb = (ushort_t*)d_ws;
    ushort_t* Qhi = wsb + 0 * NE;
    ushort_t* Qlo = wsb + 1 * NE;
    ushort_t* Khi = wsb + 2 * NE;
    ushort_t* Klo = wsb + 3 * NE;
    ushort_t* Vt  = wsb + 4 * NE;   // [b,h,d,s]
    ushort_t* wb  = wsb + 5 * NE;   // split weights: 8 x 1M
    const size_t WN = (size_t)CEMB * CEMB;
    ushort_t* hq = wb + 0 * WN;  ushort_t* lq = wb + 1 * WN;
    ushort_t* hk = wb + 2 * WN;  ushort_t* lk = wb + 3 * WN;
    ushort_t* hv = wb + 4 * WN;  ushort_t* lv = wb + 5 * WN;
    ushort_t* ho = wb + 6 * WN;  ushort_t* lo_ = wb + 7 * WN;

    const int M = CB * CS;  // 4096
    dim3 blk(256);

    convert_wt<<<dim3(16, 16, 4), blk, 0, stream>>>(
        Wq, Wk, Wv, Wo, hq, lq, hk, lk, hv, lv, ho, lo_);

    qkv_proj<<<dim3(CEMB / 128, M / 128, 3), blk, 0, stream>>>(
        q, k, v, hq, lq, hk, lk, hv, lv, Qhi, Qlo, Khi, Klo, Vt);

    flash_mfma<<<dim3(32 * CB * CH), blk, 0, stream>>>(
        Qhi, Qlo, Khi, Klo, Vt, attn, masked);

    out_proj<<<dim3(CEMB / 128, M / 128), blk, 0, stream>>>(attn, ho, lo_, out);
}

// Round 9
// 356.964 us; speedup vs baseline: 1.3011x; 1.3011x over previous
//
#include <hip/hip_runtime.h>
#include <math.h>

// Problem constants (fixed by the reference)
constexpr int CB = 2, CS = 2048, CD = 1024, CH = 16, CHD = 64;
constexpr int CEMB = 1024;

typedef unsigned short ushort_t;
typedef __attribute__((ext_vector_type(8))) short short8;   // 8 bf16 = 4 VGPR
typedef __attribute__((ext_vector_type(4))) float f32x4;    // MFMA acc

// fp32 -> bf16 round-to-nearest-even (finite data only)
__device__ __forceinline__ ushort_t f2bf(float x) {
    unsigned int u = __builtin_bit_cast(unsigned int, x);
    u = u + 0x7fffu + ((u >> 16) & 1u);
    return (ushort_t)(u >> 16);
}
__device__ __forceinline__ float bf2f(ushort_t h) {
    unsigned int u = ((unsigned int)h) << 16;
    return __builtin_bit_cast(float, u);
}

// ===========================================================================
// Weight pre-pass: W[k][n] fp32 -> WT_hi[n][k], WT_lo[n][k] bf16 (split).
// ===========================================================================
__global__ __launch_bounds__(256) void convert_wt(
    const float* __restrict__ W0, const float* __restrict__ W1,
    const float* __restrict__ W2, const float* __restrict__ W3,
    ushort_t* __restrict__ H0, ushort_t* __restrict__ L0,
    ushort_t* __restrict__ H1, ushort_t* __restrict__ L1,
    ushort_t* __restrict__ H2, ushort_t* __restrict__ L2,
    ushort_t* __restrict__ H3, ushort_t* __restrict__ L3) {
    const float* W;
    ushort_t* Hd;
    ushort_t* Ld;
    switch (blockIdx.z) {
        case 0: W = W0; Hd = H0; Ld = L0; break;
        case 1: W = W1; Hd = H1; Ld = L1; break;
        case 2: W = W2; Hd = H2; Ld = L2; break;
        default: W = W3; Hd = H3; Ld = L3; break;
    }
    const int n0 = blockIdx.x * 64, k0 = blockIdx.y * 64;
    __shared__ float Ls[64][65];
    const int t = threadIdx.x;
#pragma unroll
    for (int rep = 0; rep < 4; rep++) {
        const int r = rep * 16 + (t >> 4);
        const int c4 = (t & 15) * 4;
        *(float4*)&Ls[r][c4] = *(const float4*)&W[(size_t)(k0 + r) * CEMB + n0 + c4];
    }
    __syncthreads();
    const int n = t >> 2, kc = (t & 3) * 16;
#pragma unroll
    for (int c = 0; c < 2; c++) {
        union { ushort_t us[8]; uint4 v; } H, L;
#pragma unroll
        for (int j = 0; j < 8; j++) {
            const float x = Ls[kc + c * 8 + j][n];
            const ushort_t h = f2bf(x);
            H.us[j] = h;
            L.us[j] = f2bf(x - bf2f(h));
        }
        const size_t dst = (size_t)(n0 + n) * CEMB + k0 + kc + c * 8;
        *(uint4*)&Hd[dst] = H.v;
        *(uint4*)&Ld[dst] = L.v;
    }
}

// ===========================================================================
// Split-bf16 MFMA GEMM: 128x128 tile, BK=32, 4 waves, 4x4 16x16x32 frags.
// Epilogue modes: 0 = fp32 row-major [M][N]
//                 1 = split bf16 scatter [b,h,s,d], pre-scaled
//                 2 = bf16 [b,h,d,s] via per-wave LDS transpose (coalesced)
// ===========================================================================
constexpr int LP = 72;  // LDS pitch in bf16 elems (144B = 9 quads, odd)

template <bool GATHER_A>
__device__ __forceinline__ void gemm_split_body(
    const float* __restrict__ A, const ushort_t* __restrict__ Bhi,
    const ushort_t* __restrict__ Blo, float* __restrict__ Cf,
    ushort_t* __restrict__ C0, ushort_t* __restrict__ C1, float scale,
    int emode, int M, int N, int K) {
    __shared__ char gpool[36864];  // staging 32KB; emode2 transpose 36KB
    ushort_t* const As_hi = (ushort_t*)gpool;
    ushort_t* const As_lo = As_hi + 128 * 32;
    ushort_t* const Bs_hi = As_lo + 128 * 32;
    ushort_t* const Bs_lo = Bs_hi + 128 * 32;
    const int tid = threadIdx.x;
    const int row0 = blockIdx.y * 128, col0 = blockIdx.x * 128;
    const int w = tid >> 6, l = tid & 63, lr = l & 15, lg = l >> 4;
    const int wm = w >> 1, wn = w & 1;

    f32x4 acc[4][4];
#pragma unroll
    for (int i = 0; i < 4; i++)
#pragma unroll
        for (int j = 0; j < 4; j++) acc[i][j] = (f32x4)(0.f);

    const int st_r = tid >> 1;
    const int st_kh = (tid & 1) * 16;

    for (int k0 = 0; k0 < K; k0 += 32) {
        {   // stage A: fp32 -> split bf16
            const int gm = row0 + st_r;
            const int gk = k0 + st_kh;
            const float* src;
            if (GATHER_A) {
                const int b_ = gm >> 11, s_ = gm & 2047;
                const int h_ = gk >> 6, d_ = gk & 63;
                src = &A[(((size_t)b_ * CH + h_) * CS + s_) * CHD + d_];
            } else {
                src = &A[(size_t)gm * K + gk];
            }
            float va[16];
#pragma unroll
            for (int r = 0; r < 4; r++)
                *(float4*)&va[r * 4] = *(const float4*)&src[r * 4];
#pragma unroll
            for (int c = 0; c < 2; c++) {
                union { ushort_t us[8]; uint4 v; } H, L;
#pragma unroll
                for (int j = 0; j < 8; j++) {
                    const float x = va[c * 8 + j];
                    const ushort_t h = f2bf(x);
                    H.us[j] = h;
                    L.us[j] = f2bf(x - bf2f(h));
                }
                const int chunk = (st_kh >> 3) + c;
                const int csw = chunk ^ ((st_r >> 1) & 3);
                *(uint4*)&As_hi[st_r * 32 + csw * 8] = H.v;
                *(uint4*)&As_lo[st_r * 32 + csw * 8] = L.v;
            }
        }
        {   // stage B: pre-split bf16 [n][k]
            const size_t base = (size_t)(col0 + st_r) * K + k0 + st_kh;
#pragma unroll
            for (int c = 0; c < 2; c++) {
                const uint4 hv = *(const uint4*)&Bhi[base + c * 8];
                const uint4 lv = *(const uint4*)&Blo[base + c * 8];
                const int chunk = (st_kh >> 3) + c;
                const int csw = chunk ^ ((st_r >> 1) & 3);
                *(uint4*)&Bs_hi[st_r * 32 + csw * 8] = hv;
                *(uint4*)&Bs_lo[st_r * 32 + csw * 8] = lv;
            }
        }
        __syncthreads();

        short8 ah[4], al[4], bh[4], bl[4];
#pragma unroll
        for (int i = 0; i < 4; i++) {
            const int r = wm * 64 + i * 16 + lr;
            const int cs = lg ^ ((r >> 1) & 3);
            ah[i] = *(const short8*)&As_hi[r * 32 + cs * 8];
            al[i] = *(const short8*)&As_lo[r * 32 + cs * 8];
        }
#pragma unroll
        for (int j = 0; j < 4; j++) {
            const int cc = wn * 64 + j * 16 + lr;
            const int cs = lg ^ ((cc >> 1) & 3);
            bh[j] = *(const short8*)&Bs_hi[cc * 32 + cs * 8];
            bl[j] = *(const short8*)&Bs_lo[cc * 32 + cs * 8];
        }
#pragma unroll
        for (int j = 0; j < 4; j++)
#pragma unroll
            for (int i = 0; i < 4; i++) {
                acc[i][j] = __builtin_amdgcn_mfma_f32_16x16x32_bf16(
                    al[i], bh[j], acc[i][j], 0, 0, 0);
                acc[i][j] = __builtin_amdgcn_mfma_f32_16x16x32_bf16(
                    ah[i], bl[j], acc[i][j], 0, 0, 0);
                acc[i][j] = __builtin_amdgcn_mfma_f32_16x16x32_bf16(
                    ah[i], bh[j], acc[i][j], 0, 0, 0);
            }
        __syncthreads();
    }

    if (emode == 2) {
        // Vt [b,h,d,s]: per-wave 64x64 transpose through LDS, uint4 stores
        // of 8 consecutive s (128B runs). Wave-private region, no barrier.
        ushort_t* const T = (ushort_t*)gpool + w * 64 * LP;
#pragma unroll
        for (int i = 0; i < 4; i++)
#pragma unroll
            for (int j = 0; j < 4; j++) {
                const unsigned int a =
                    (unsigned int)f2bf(acc[i][j][0]) |
                    ((unsigned int)f2bf(acc[i][j][1]) << 16);
                const unsigned int b =
                    (unsigned int)f2bf(acc[i][j][2]) |
                    ((unsigned int)f2bf(acc[i][j][3]) << 16);
                *(uint2*)&T[(j * 16 + lr) * LP + i * 16 + 4 * lg] =
                    make_uint2(a, b);
            }
#pragma unroll
        for (int grp = 0; grp < 8; grp++) {
            const int dl = (l >> 3) + grp * 8;
            const int s8 = (l & 7) * 8;
            const uint4 vv = *(const uint4*)&T[dl * LP + s8];
            const int gm = row0 + wm * 64 + s8;
            const int b_ = gm >> 11, ss = gm & 2047;
            const int dg = col0 + wn * 64 + dl;
            const int h_ = dg >> 6, hd = dg & 63;
            *(uint4*)&C0[(((size_t)b_ * CH + h_) * CHD + hd) * CS + ss] = vv;
        }
        return;
    }

#pragma unroll
    for (int i = 0; i < 4; i++)
#pragma unroll
        for (int j = 0; j < 4; j++) {
            const int cc = col0 + wn * 64 + j * 16 + lr;
#pragma unroll
            for (int r = 0; r < 4; r++) {
                const int cr = row0 + wm * 64 + i * 16 + lg * 4 + r;
                const float vv = acc[i][j][r];
                if (emode == 0) {
                    Cf[(size_t)cr * N + cc] = vv;
                } else {  // emode 1: split bf16 scatter [b,h,s,d]
                    const int b_ = cr >> 11, s_ = cr & 2047;
                    const int h_ = cc >> 6, d_ = cc & 63;
                    const size_t idx =
                        (((size_t)b_ * CH + h_) * CS + s_) * CHD + d_;
                    const float x = vv * scale;
                    const ushort_t hb = f2bf(x);
                    C0[idx] = hb;
                    C1[idx] = f2bf(x - bf2f(hb));
                }
            }
        }
}

__global__ __launch_bounds__(256, 2) void qkv_proj(
    const float* __restrict__ q, const float* __restrict__ k,
    const float* __restrict__ v,
    const ushort_t* __restrict__ hq, const ushort_t* __restrict__ lq,
    const ushort_t* __restrict__ hk, const ushort_t* __restrict__ lk,
    const ushort_t* __restrict__ hv, const ushort_t* __restrict__ lv,
    ushort_t* __restrict__ Qhi, ushort_t* __restrict__ Qlo,
    ushort_t* __restrict__ Khi, ushort_t* __restrict__ Klo,
    ushort_t* __restrict__ Vt) {
    const float* A;
    const ushort_t* Bh;
    const ushort_t* Bl;
    ushort_t* C0;
    ushort_t* C1 = nullptr;
    float scale = 1.0f;
    int emode;
    if (blockIdx.z == 0) {
        A = q; Bh = hq; Bl = lq; C0 = Qhi; C1 = Qlo; scale = 0.125f; emode = 1;
    } else if (blockIdx.z == 1) {
        A = k; Bh = hk; Bl = lk; C0 = Khi; C1 = Klo; emode = 1;
    } else {
        A = v; Bh = hv; Bl = lv; C0 = Vt; emode = 2;
    }
    gemm_split_body<false>(A, Bh, Bl, nullptr, C0, C1, scale, emode,
                           CB * CS, CEMB, CD);
}

__global__ __launch_bounds__(256, 2) void out_proj(
    const float* __restrict__ attn, const ushort_t* __restrict__ ho,
    const ushort_t* __restrict__ lo_, float* __restrict__ out) {
    gemm_split_body<true>(attn, ho, lo_, out, nullptr, nullptr, 1.0f, 0,
                          CB * CS, CEMB, CEMB);
}

// ===========================================================================
// MFMA flash attention, swapped operands, SEQUENTIAL TWO-TILE blocks.
// Grid (16, 32): block j of a bh does q-tile (31-j) [32-j k-iters] THEN
// q-tile j [j+1 k-iters] = uniform 33 iterations per block (64 unmasked).
// All 4 waves active every iteration (16 q-rows each). Phase B's k-tiles
// are a subset of phase A's -> L2-warm. XCD swizzle: 4 bh per XCD.
// S^T = mfma(K,Q): lane owns one q-row; softmax = in-reg + 2 shuffles.
// Per-wave P/T region (pitch 136 bf16 / 68 f32): all b128 reads (K,V,P)
// land uniform 8 accesses/bank (the 1KB wave minimum, conflict-free).
// O epilogue per phase: per-wave LDS transpose -> coalesced float4 stores.
// ===========================================================================
constexpr int PB = 136;  // per-wave P/T pitch, bf16 units
constexpr int PF = 68;   // same region, f32 units

__global__ __launch_bounds__(256, 2) void flash_mfma(
    const ushort_t* __restrict__ Qhi, const ushort_t* __restrict__ Qlo,
    const ushort_t* __restrict__ Khi, const ushort_t* __restrict__ Klo,
    const ushort_t* __restrict__ Vt, float* __restrict__ O,
    const int* __restrict__ maskedp) {
    __shared__ ushort_t lds[3 * 64 * LP + 4 * 16 * PB];  // 27KB + 17.4KB
    ushort_t* const Ks_hi = lds;
    ushort_t* const Ks_lo = lds + 64 * LP;
    ushort_t* const Vs = lds + 2 * 64 * LP;

    const int tid = threadIdx.x;
    const int w = tid >> 6, l = tid & 63, lr = l & 15, lg = l >> 4;
    ushort_t* const Ps = lds + 3 * 64 * LP + w * 16 * PB;  // wave-private
    float* const T = (float*)Ps;                            // alias (fp32)
    const int masked = maskedp[0];

    // XCD swizzle: 512 blocks; XCD c gets sid [c*64,(c+1)*64) = 4 bh chunk
    const int id = blockIdx.x + 16 * blockIdx.y;
    const int sid = (id & 7) * 64 + (id >> 3);
    const int jj = sid & 15;
    const int bh = sid >> 4;
    const int qa = 31 - jj;  // phase A q-tile (long)
    const size_t bhoff = (size_t)bh * CS * CHD;

    const int itersA = masked ? (32 - jj) : 32;
    const int TOT = itersA + (masked ? (jj + 1) : 32);

    short8 qh[2], ql[2];
    auto loadQ = [&](int qt) {
        const int q0 = qt * 64 + w * 16;
#pragma unroll
        for (int ds = 0; ds < 2; ds++) {
            const size_t off =
                bhoff + (size_t)(q0 + lr) * CHD + ds * 32 + lg * 8;
            qh[ds] = *(const short8*)&Qhi[off];
            ql[ds] = *(const short8*)&Qlo[off];
        }
    };

    f32x4 Oacc[4];
    float m_i, l_i;
    auto resetState = [&]() {
        m_i = -INFINITY;
        l_i = 0.f;
#pragma unroll
        for (int df = 0; df < 4; df++) Oacc[df] = (f32x4)(0.f);
    };

    auto writeO = [&](int qt) {
        const int q0 = qt * 64 + w * 16;
        const float inv = 1.0f / l_i;
#pragma unroll
        for (int df = 0; df < 4; df++)
            *(f32x4*)&T[lr * PF + df * 16 + 4 * lg] = Oacc[df] * inv;
#pragma unroll
        for (int grp = 0; grp < 4; grp++) {
            const int qrow = grp * 4 + lg;
            const float4 vv = *(const float4*)&T[qrow * PF + lr * 4];
            *(float4*)&O[bhoff + (size_t)(q0 + qrow) * CHD + lr * 4] = vv;
        }
    };

    loadQ(qa);
    resetState();

    const int st_r = tid >> 2;
    const int st_c = tid & 3;

    // prefetch k-tile 0
    uint4 pk_hi[2], pk_lo[2], pv[2];
#pragma unroll
    for (int p = 0; p < 2; p++) {
        const int c = st_c + p * 4;
        const size_t kgl = bhoff + (size_t)st_r * CHD + c * 8;
        pk_hi[p] = *(const uint4*)&Khi[kgl];
        pk_lo[p] = *(const uint4*)&Klo[kgl];
        const size_t vgl = ((size_t)bh * CHD + st_r) * CS + c * 8;
        pv[p] = *(const uint4*)&Vt[vgl];
    }

    for (int it = 0; it < TOT; it++) {
        const bool inB = it >= itersA;
        const int t = inB ? (it - itersA) : it;
        const int qtcur = inB ? jj : qa;

        // ---- write prefetched K(hi,lo)/V^T regs to LDS ----
#pragma unroll
        for (int p = 0; p < 2; p++) {
            const int c = st_c + p * 4;
            *(uint4*)&Ks_hi[st_r * LP + c * 8] = pk_hi[p];
            *(uint4*)&Ks_lo[st_r * LP + c * 8] = pk_lo[p];
            *(uint4*)&Vs[st_r * LP + c * 8] = pv[p];
        }
        __syncthreads();

        // ---- issue next k-tile's loads (latency hides under compute) ----
        const int nit = it + 1;
        if (nit < TOT) {
            const int nt = (nit >= itersA) ? (nit - itersA) : nit;
#pragma unroll
            for (int p = 0; p < 2; p++) {
                const int c = st_c + p * 4;
                const size_t kgl =
                    bhoff + (size_t)(nt * 64 + st_r) * CHD + c * 8;
                pk_hi[p] = *(const uint4*)&Khi[kgl];
                pk_lo[p] = *(const uint4*)&Klo[kgl];
                const size_t vgl =
                    ((size_t)bh * CHD + st_r) * CS + nt * 64 + c * 8;
                pv[p] = *(const uint4*)&Vt[vgl];
            }
        }

        // ---- S^T = K @ Q^T (split: Kh*Ql + Kl*Qh + Kh*Qh) ----
        f32x4 S[4];
#pragma unroll
        for (int kf = 0; kf < 4; kf++) S[kf] = (f32x4)(0.f);
#pragma unroll
        for (int ds = 0; ds < 2; ds++) {
            short8 kh[4], kl[4];
#pragma unroll
            for (int kf = 0; kf < 4; kf++) {
                const int off = (kf * 16 + lr) * LP + ds * 32 + lg * 8;
                kh[kf] = *(const short8*)&Ks_hi[off];
                kl[kf] = *(const short8*)&Ks_lo[off];
            }
#pragma unroll
            for (int kf = 0; kf < 4; kf++) {
                S[kf] = __builtin_amdgcn_mfma_f32_16x16x32_bf16(
                    kh[kf], ql[ds], S[kf], 0, 0, 0);
                S[kf] = __builtin_amdgcn_mfma_f32_16x16x32_bf16(
                    kl[kf], qh[ds], S[kf], 0, 0, 0);
                S[kf] = __builtin_amdgcn_mfma_f32_16x16x32_bf16(
                    kh[kf], qh[ds], S[kf], 0, 0, 0);
            }
        }

        // ---- causal mask (diagonal k-tile of the current phase) ----
        if (masked && t == qtcur) {
            const int qg = qtcur * 64 + w * 16 + lr;
#pragma unroll
            for (int kf = 0; kf < 4; kf++)
#pragma unroll
                for (int r = 0; r < 4; r++) {
                    const int kg = t * 64 + kf * 16 + 4 * lg + r;
                    if (kg > qg) S[kf][r] = -INFINITY;
                }
        }

        // ---- online softmax: in-reg over 16 + 2 shuffles across lg ----
        {
            float mt = -INFINITY;
#pragma unroll
            for (int kf = 0; kf < 4; kf++)
#pragma unroll
                for (int r = 0; r < 4; r++) mt = fmaxf(mt, S[kf][r]);
            mt = fmaxf(mt, __shfl_xor(mt, 16));
            mt = fmaxf(mt, __shfl_xor(mt, 32));
            const float mn = fmaxf(m_i, mt);
            const float corr = __expf(m_i - mn);
            float rs = 0.f;
#pragma unroll
            for (int kf = 0; kf < 4; kf++)
#pragma unroll
                for (int r = 0; r < 4; r++) {
                    const float p = __expf(S[kf][r] - mn);
                    S[kf][r] = p;
                    rs += p;
                }
            rs += __shfl_xor(rs, 16);
            rs += __shfl_xor(rs, 32);
            l_i = l_i * corr + rs;
            m_i = mn;
#pragma unroll
            for (int df = 0; df < 4; df++) Oacc[df] *= corr;
        }

        // ---- pack P: same-lane regs -> one b64 write per kf ----
#pragma unroll
        for (int kf = 0; kf < 4; kf++) {
            const unsigned int a = (unsigned int)f2bf(S[kf][0]) |
                                   ((unsigned int)f2bf(S[kf][1]) << 16);
            const unsigned int b = (unsigned int)f2bf(S[kf][2]) |
                                   ((unsigned int)f2bf(S[kf][3]) << 16);
            *(uint2*)&Ps[lr * PB + kf * 16 + 4 * lg] = make_uint2(a, b);
        }

        // ---- O^T += V^T @ P^T (per-wave private P, no barrier) ----
#pragma unroll
        for (int ks = 0; ks < 2; ks++) {
            short8 vb[4];
#pragma unroll
            for (int df = 0; df < 4; df++)
                vb[df] = *(const short8*)&Vs[(df * 16 + lr) * LP + ks * 32 +
                                             lg * 8];
            const short8 pb = *(const short8*)&Ps[lr * PB + ks * 32 + lg * 8];
#pragma unroll
            for (int df = 0; df < 4; df++)
                Oacc[df] = __builtin_amdgcn_mfma_f32_16x16x32_bf16(
                    vb[df], pb, Oacc[df], 0, 0, 0);
        }

        // ---- phase A done: write its O, reset, switch to tile B ----
        if (it == itersA - 1) {
            writeO(qa);
            resetState();
            loadQ(jj);
        }
        __syncthreads();  // protect K/V LDS for next iteration
    }

    writeO(jj);
}

// ===========================================================================
extern "C" void kernel_launch(void* const* d_in, const int* in_sizes, int n_in,
                              void* d_out, int out_size, void* d_ws,
                              size_t ws_size, hipStream_t stream) {
    const float* q  = (const float*)d_in[0];
    const float* k  = (const float*)d_in[1];
    const float* v  = (const float*)d_in[2];
    const float* Wq = (const float*)d_in[3];
    const float* Wk = (const float*)d_in[4];
    const float* Wv = (const float*)d_in[5];
    const float* Wo = (const float*)d_in[6];
    const int* masked = (const int*)d_in[7];

    float* out  = (float*)d_out;                 // [B,S,1024]
    float* attn = out + (size_t)CB * CS * CEMB;  // [B,H,S,64] (2nd output)

    // workspace layout (bf16 buffers, all 16B aligned):
    const size_t NE = (size_t)CB * CS * CEMB;  // 4M elems per tensor
    ushort_t* wsb = (ushort_t*)d_ws;
    ushort_t* Qhi = wsb + 0 * NE;
    ushort_t* Qlo = wsb + 1 * NE;
    ushort_t* Khi = wsb + 2 * NE;
    ushort_t* Klo = wsb + 3 * NE;
    ushort_t* Vt  = wsb + 4 * NE;   // [b,h,d,s]
    ushort_t* wb  = wsb + 5 * NE;   // split weights: 8 x 1M
    const size_t WN = (size_t)CEMB * CEMB;
    ushort_t* hq = wb + 0 * WN;  ushort_t* lq = wb + 1 * WN;
    ushort_t* hk = wb + 2 * WN;  ushort_t* lk = wb + 3 * WN;
    ushort_t* hv = wb + 4 * WN;  ushort_t* lv = wb + 5 * WN;
    ushort_t* ho = wb + 6 * WN;  ushort_t* lo_ = wb + 7 * WN;

    const int M = CB * CS;  // 4096
    dim3 blk(256);

    convert_wt<<<dim3(16, 16, 4), blk, 0, stream>>>(
        Wq, Wk, Wv, Wo, hq, lq, hk, lk, hv, lv, ho, lo_);

    qkv_proj<<<dim3(CEMB / 128, M / 128, 3), blk, 0, stream>>>(
        q, k, v, hq, lq, hk, lk, hv, lv, Qhi, Qlo, Khi, Klo, Vt);

    flash_mfma<<<dim3(16, CB * CH), blk, 0, stream>>>(
        Qhi, Qlo, Khi, Klo, Vt, attn, masked);

    out_proj<<<dim3(CEMB / 128, M / 128), blk, 0, stream>>>(attn, ho, lo_, out);
}

// Round 10
// 349.337 us; speedup vs baseline: 1.3295x; 1.0218x over previous
//
#include <hip/hip_runtime.h>
#include <math.h>

// Problem constants (fixed by the reference)
constexpr int CB = 2, CS = 2048, CD = 1024, CH = 16, CHD = 64;
constexpr int CEMB = 1024;

typedef unsigned short ushort_t;
typedef __attribute__((ext_vector_type(8))) short short8;   // 8 bf16 = 4 VGPR
typedef __attribute__((ext_vector_type(4))) float f32x4;    // MFMA acc

// fp32 -> bf16 round-to-nearest-even (finite data only)
__device__ __forceinline__ ushort_t f2bf(float x) {
    unsigned int u = __builtin_bit_cast(unsigned int, x);
    u = u + 0x7fffu + ((u >> 16) & 1u);
    return (ushort_t)(u >> 16);
}
__device__ __forceinline__ float bf2f(ushort_t h) {
    unsigned int u = ((unsigned int)h) << 16;
    return __builtin_bit_cast(float, u);
}

// ===========================================================================
// Weight pre-pass: W[k][n] fp32 -> WT_hi[n][k], WT_lo[n][k] bf16 (split).
// ===========================================================================
__global__ __launch_bounds__(256) void convert_wt(
    const float* __restrict__ W0, const float* __restrict__ W1,
    const float* __restrict__ W2, const float* __restrict__ W3,
    ushort_t* __restrict__ H0, ushort_t* __restrict__ L0,
    ushort_t* __restrict__ H1, ushort_t* __restrict__ L1,
    ushort_t* __restrict__ H2, ushort_t* __restrict__ L2,
    ushort_t* __restrict__ H3, ushort_t* __restrict__ L3) {
    const float* W;
    ushort_t* Hd;
    ushort_t* Ld;
    switch (blockIdx.z) {
        case 0: W = W0; Hd = H0; Ld = L0; break;
        case 1: W = W1; Hd = H1; Ld = L1; break;
        case 2: W = W2; Hd = H2; Ld = L2; break;
        default: W = W3; Hd = H3; Ld = L3; break;
    }
    const int n0 = blockIdx.x * 64, k0 = blockIdx.y * 64;
    __shared__ float Ls[64][65];
    const int t = threadIdx.x;
#pragma unroll
    for (int rep = 0; rep < 4; rep++) {
        const int r = rep * 16 + (t >> 4);
        const int c4 = (t & 15) * 4;
        *(float4*)&Ls[r][c4] = *(const float4*)&W[(size_t)(k0 + r) * CEMB + n0 + c4];
    }
    __syncthreads();
    const int n = t >> 2, kc = (t & 3) * 16;
#pragma unroll
    for (int c = 0; c < 2; c++) {
        union { ushort_t us[8]; uint4 v; } H, L;
#pragma unroll
        for (int j = 0; j < 8; j++) {
            const float x = Ls[kc + c * 8 + j][n];
            const ushort_t h = f2bf(x);
            H.us[j] = h;
            L.us[j] = f2bf(x - bf2f(h));
        }
        const size_t dst = (size_t)(n0 + n) * CEMB + k0 + kc + c * 8;
        *(uint4*)&Hd[dst] = H.v;
        *(uint4*)&Ld[dst] = L.v;
    }
}

// ===========================================================================
// Split-bf16 MFMA GEMM body: 128x128 tile, BK=32, 4 waves, 4x4 16x16x32.
// full=true : 3-product split (al*bh + ah*bl + ah*bh), fp32-accurate.
// full=false: plain bf16 (1 product) — for outputs that round to bf16 anyway.
// Epilogue modes: 0 = fp32 row-major [M][N]
//                 1 = split bf16 scatter [b,h,s,d], pre-scaled
//                 2 = bf16 [b,h,d,s] via per-wave LDS transpose (coalesced)
// row0/col0 passed in (callers do XCD-aware block remapping).
// ===========================================================================
constexpr int LP = 72;  // LDS pitch in bf16 elems (144B = 9 quads, odd)

template <bool GATHER_A>
__device__ __forceinline__ void gemm_split_body(
    const float* __restrict__ A, const ushort_t* __restrict__ Bhi,
    const ushort_t* __restrict__ Blo, float* __restrict__ Cf,
    ushort_t* __restrict__ C0, ushort_t* __restrict__ C1, float scale,
    int emode, bool full, int row0, int col0, int M, int N, int K) {
    __shared__ char gpool[36864];  // staging 32KB; emode2 transpose 36KB
    ushort_t* const As_hi = (ushort_t*)gpool;
    ushort_t* const As_lo = As_hi + 128 * 32;
    ushort_t* const Bs_hi = As_lo + 128 * 32;
    ushort_t* const Bs_lo = Bs_hi + 128 * 32;
    const int tid = threadIdx.x;
    const int w = tid >> 6, l = tid & 63, lr = l & 15, lg = l >> 4;
    const int wm = w >> 1, wn = w & 1;

    f32x4 acc[4][4];
#pragma unroll
    for (int i = 0; i < 4; i++)
#pragma unroll
        for (int j = 0; j < 4; j++) acc[i][j] = (f32x4)(0.f);

    const int st_r = tid >> 1;
    const int st_kh = (tid & 1) * 16;

    for (int k0 = 0; k0 < K; k0 += 32) {
        {   // stage A: fp32 -> split bf16 (hi only when !full)
            const int gm = row0 + st_r;
            const int gk = k0 + st_kh;
            const float* src;
            if (GATHER_A) {
                const int b_ = gm >> 11, s_ = gm & 2047;
                const int h_ = gk >> 6, d_ = gk & 63;
                src = &A[(((size_t)b_ * CH + h_) * CS + s_) * CHD + d_];
            } else {
                src = &A[(size_t)gm * K + gk];
            }
            float va[16];
#pragma unroll
            for (int r = 0; r < 4; r++)
                *(float4*)&va[r * 4] = *(const float4*)&src[r * 4];
#pragma unroll
            for (int c = 0; c < 2; c++) {
                union { ushort_t us[8]; uint4 v; } H, L;
#pragma unroll
                for (int j = 0; j < 8; j++) {
                    const float x = va[c * 8 + j];
                    const ushort_t h = f2bf(x);
                    H.us[j] = h;
                    L.us[j] = f2bf(x - bf2f(h));
                }
                const int chunk = (st_kh >> 3) + c;
                const int csw = chunk ^ ((st_r >> 1) & 3);
                *(uint4*)&As_hi[st_r * 32 + csw * 8] = H.v;
                if (full) *(uint4*)&As_lo[st_r * 32 + csw * 8] = L.v;
            }
        }
        {   // stage B: pre-split bf16 [n][k] (hi only when !full)
            const size_t base = (size_t)(col0 + st_r) * K + k0 + st_kh;
#pragma unroll
            for (int c = 0; c < 2; c++) {
                const int chunk = (st_kh >> 3) + c;
                const int csw = chunk ^ ((st_r >> 1) & 3);
                *(uint4*)&Bs_hi[st_r * 32 + csw * 8] =
                    *(const uint4*)&Bhi[base + c * 8];
                if (full)
                    *(uint4*)&Bs_lo[st_r * 32 + csw * 8] =
                        *(const uint4*)&Blo[base + c * 8];
            }
        }
        __syncthreads();

        short8 ah[4], al[4], bh[4], bl[4];
#pragma unroll
        for (int i = 0; i < 4; i++) {
            const int r = wm * 64 + i * 16 + lr;
            const int cs = lg ^ ((r >> 1) & 3);
            ah[i] = *(const short8*)&As_hi[r * 32 + cs * 8];
            if (full) al[i] = *(const short8*)&As_lo[r * 32 + cs * 8];
        }
#pragma unroll
        for (int j = 0; j < 4; j++) {
            const int cc = wn * 64 + j * 16 + lr;
            const int cs = lg ^ ((cc >> 1) & 3);
            bh[j] = *(const short8*)&Bs_hi[cc * 32 + cs * 8];
            if (full) bl[j] = *(const short8*)&Bs_lo[cc * 32 + cs * 8];
        }
#pragma unroll
        for (int j = 0; j < 4; j++)
#pragma unroll
            for (int i = 0; i < 4; i++) {
                if (full) {
                    acc[i][j] = __builtin_amdgcn_mfma_f32_16x16x32_bf16(
                        al[i], bh[j], acc[i][j], 0, 0, 0);
                    acc[i][j] = __builtin_amdgcn_mfma_f32_16x16x32_bf16(
                        ah[i], bl[j], acc[i][j], 0, 0, 0);
                }
                acc[i][j] = __builtin_amdgcn_mfma_f32_16x16x32_bf16(
                    ah[i], bh[j], acc[i][j], 0, 0, 0);
            }
        __syncthreads();
    }

    if (emode == 2) {
        // Vt [b,h,d,s]: per-wave 64x64 transpose through LDS, uint4 stores
        // of 8 consecutive s (128B runs). Wave-private region, no barrier.
        ushort_t* const T = (ushort_t*)gpool + w * 64 * LP;
#pragma unroll
        for (int i = 0; i < 4; i++)
#pragma unroll
            for (int j = 0; j < 4; j++) {
                const unsigned int a =
                    (unsigned int)f2bf(acc[i][j][0]) |
                    ((unsigned int)f2bf(acc[i][j][1]) << 16);
                const unsigned int b =
                    (unsigned int)f2bf(acc[i][j][2]) |
                    ((unsigned int)f2bf(acc[i][j][3]) << 16);
                *(uint2*)&T[(j * 16 + lr) * LP + i * 16 + 4 * lg] =
                    make_uint2(a, b);
            }
#pragma unroll
        for (int grp = 0; grp < 8; grp++) {
            const int dl = (l >> 3) + grp * 8;
            const int s8 = (l & 7) * 8;
            const uint4 vv = *(const uint4*)&T[dl * LP + s8];
            const int gm = row0 + wm * 64 + s8;
            const int b_ = gm >> 11, ss = gm & 2047;
            const int dg = col0 + wn * 64 + dl;
            const int h_ = dg >> 6, hd = dg & 63;
            *(uint4*)&C0[(((size_t)b_ * CH + h_) * CHD + hd) * CS + ss] = vv;
        }
        return;
    }

#pragma unroll
    for (int i = 0; i < 4; i++)
#pragma unroll
        for (int j = 0; j < 4; j++) {
            const int cc = col0 + wn * 64 + j * 16 + lr;
#pragma unroll
            for (int r = 0; r < 4; r++) {
                const int cr = row0 + wm * 64 + i * 16 + lg * 4 + r;
                const float vv = acc[i][j][r];
                if (emode == 0) {
                    Cf[(size_t)cr * N + cc] = vv;
                } else {  // emode 1: split bf16 scatter [b,h,s,d]
                    const int b_ = cr >> 11, s_ = cr & 2047;
                    const int h_ = cc >> 6, d_ = cc & 63;
                    const size_t idx =
                        (((size_t)b_ * CH + h_) * CS + s_) * CHD + d_;
                    const float x = vv * scale;
                    const ushort_t hb = f2bf(x);
                    C0[idx] = hb;
                    C1[idx] = f2bf(x - bf2f(hb));
                }
            }
        }
}

// Fused Q/K/V projections, XCD-aware 1-D grid (768 blocks):
// id = (row + 32*z) + 96*col  =>  id%8 = row%8, so all 8 col-tiles of one
// A-row-panel (512KB fp32) land on ONE XCD and hit its L2 after first use.
// V (z==2) uses plain bf16 (full=false): output is rounded to bf16 anyway.
__global__ __launch_bounds__(256, 2) void qkv_proj(
    const float* __restrict__ q, const float* __restrict__ k,
    const float* __restrict__ v,
    const ushort_t* __restrict__ hq, const ushort_t* __restrict__ lq,
    const ushort_t* __restrict__ hk, const ushort_t* __restrict__ lk,
    const ushort_t* __restrict__ hv, const ushort_t* __restrict__ lv,
    ushort_t* __restrict__ Qhi, ushort_t* __restrict__ Qlo,
    ushort_t* __restrict__ Khi, ushort_t* __restrict__ Klo,
    ushort_t* __restrict__ Vt) {
    const int id = blockIdx.x;
    const int col = id / 96;
    const int rem = id % 96;
    const int z = rem >> 5;
    const int row = rem & 31;
    const float* A;
    const ushort_t* Bh;
    const ushort_t* Bl;
    ushort_t* C0;
    ushort_t* C1 = nullptr;
    float scale = 1.0f;
    int emode;
    bool full = true;
    if (z == 0) {
        A = q; Bh = hq; Bl = lq; C0 = Qhi; C1 = Qlo; scale = 0.125f; emode = 1;
    } else if (z == 1) {
        A = k; Bh = hk; Bl = lk; C0 = Khi; C1 = Klo; emode = 1;
    } else {
        A = v; Bh = hv; Bl = lv; C0 = Vt; emode = 2; full = false;
    }
    gemm_split_body<false>(A, Bh, Bl, nullptr, C0, C1, scale, emode, full,
                           row * 128, col * 128, CB * CS, CEMB, CD);
}

// Output projection, XCD-aware 1-D grid (256): id = row + 32*col.
__global__ __launch_bounds__(256, 2) void out_proj(
    const float* __restrict__ attn, const ushort_t* __restrict__ ho,
    const ushort_t* __restrict__ lo_, float* __restrict__ out) {
    const int id = blockIdx.x;
    const int col = id >> 5;
    const int row = id & 31;
    gemm_split_body<true>(attn, ho, lo_, out, nullptr, nullptr, 1.0f, 0, true,
                          row * 128, col * 128, CB * CS, CEMB, CEMB);
}

// ===========================================================================
// MFMA flash attention, swapped operands, SEQUENTIAL TWO-TILE blocks.
// (structure unchanged from R9 = 123us; this round adds only s_setprio
//  around the MFMA clusters — T5, clean per-dispatch A/B.)
// ===========================================================================
constexpr int PB = 136;  // per-wave P/T pitch, bf16 units
constexpr int PF = 68;   // same region, f32 units

__global__ __launch_bounds__(256, 2) void flash_mfma(
    const ushort_t* __restrict__ Qhi, const ushort_t* __restrict__ Qlo,
    const ushort_t* __restrict__ Khi, const ushort_t* __restrict__ Klo,
    const ushort_t* __restrict__ Vt, float* __restrict__ O,
    const int* __restrict__ maskedp) {
    __shared__ ushort_t lds[3 * 64 * LP + 4 * 16 * PB];  // 27KB + 17.4KB
    ushort_t* const Ks_hi = lds;
    ushort_t* const Ks_lo = lds + 64 * LP;
    ushort_t* const Vs = lds + 2 * 64 * LP;

    const int tid = threadIdx.x;
    const int w = tid >> 6, l = tid & 63, lr = l & 15, lg = l >> 4;
    ushort_t* const Ps = lds + 3 * 64 * LP + w * 16 * PB;  // wave-private
    float* const T = (float*)Ps;                            // alias (fp32)
    const int masked = maskedp[0];

    // XCD swizzle: 512 blocks; XCD c gets sid [c*64,(c+1)*64) = 4 bh chunk
    const int id = blockIdx.x + 16 * blockIdx.y;
    const int sid = (id & 7) * 64 + (id >> 3);
    const int jj = sid & 15;
    const int bh = sid >> 4;
    const int qa = 31 - jj;  // phase A q-tile (long)
    const size_t bhoff = (size_t)bh * CS * CHD;

    const int itersA = masked ? (32 - jj) : 32;
    const int TOT = itersA + (masked ? (jj + 1) : 32);

    short8 qh[2], ql[2];
    auto loadQ = [&](int qt) {
        const int q0 = qt * 64 + w * 16;
#pragma unroll
        for (int ds = 0; ds < 2; ds++) {
            const size_t off =
                bhoff + (size_t)(q0 + lr) * CHD + ds * 32 + lg * 8;
            qh[ds] = *(const short8*)&Qhi[off];
            ql[ds] = *(const short8*)&Qlo[off];
        }
    };

    f32x4 Oacc[4];
    float m_i, l_i;
    auto resetState = [&]() {
        m_i = -INFINITY;
        l_i = 0.f;
#pragma unroll
        for (int df = 0; df < 4; df++) Oacc[df] = (f32x4)(0.f);
    };

    auto writeO = [&](int qt) {
        const int q0 = qt * 64 + w * 16;
        const float inv = 1.0f / l_i;
#pragma unroll
        for (int df = 0; df < 4; df++)
            *(f32x4*)&T[lr * PF + df * 16 + 4 * lg] = Oacc[df] * inv;
#pragma unroll
        for (int grp = 0; grp < 4; grp++) {
            const int qrow = grp * 4 + lg;
            const float4 vv = *(const float4*)&T[qrow * PF + lr * 4];
            *(float4*)&O[bhoff + (size_t)(q0 + qrow) * CHD + lr * 4] = vv;
        }
    };

    loadQ(qa);
    resetState();

    const int st_r = tid >> 2;
    const int st_c = tid & 3;

    // prefetch k-tile 0
    uint4 pk_hi[2], pk_lo[2], pv[2];
#pragma unroll
    for (int p = 0; p < 2; p++) {
        const int c = st_c + p * 4;
        const size_t kgl = bhoff + (size_t)st_r * CHD + c * 8;
        pk_hi[p] = *(const uint4*)&Khi[kgl];
        pk_lo[p] = *(const uint4*)&Klo[kgl];
        const size_t vgl = ((size_t)bh * CHD + st_r) * CS + c * 8;
        pv[p] = *(const uint4*)&Vt[vgl];
    }

    for (int it = 0; it < TOT; it++) {
        const bool inB = it >= itersA;
        const int t = inB ? (it - itersA) : it;
        const int qtcur = inB ? jj : qa;

        // ---- write prefetched K(hi,lo)/V^T regs to LDS ----
#pragma unroll
        for (int p = 0; p < 2; p++) {
            const int c = st_c + p * 4;
            *(uint4*)&Ks_hi[st_r * LP + c * 8] = pk_hi[p];
            *(uint4*)&Ks_lo[st_r * LP + c * 8] = pk_lo[p];
            *(uint4*)&Vs[st_r * LP + c * 8] = pv[p];
        }
        __syncthreads();

        // ---- issue next k-tile's loads (latency hides under compute) ----
        const int nit = it + 1;
        if (nit < TOT) {
            const int nt = (nit >= itersA) ? (nit - itersA) : nit;
#pragma unroll
            for (int p = 0; p < 2; p++) {
                const int c = st_c + p * 4;
                const size_t kgl =
                    bhoff + (size_t)(nt * 64 + st_r) * CHD + c * 8;
                pk_hi[p] = *(const uint4*)&Khi[kgl];
                pk_lo[p] = *(const uint4*)&Klo[kgl];
                const size_t vgl =
                    ((size_t)bh * CHD + st_r) * CS + nt * 64 + c * 8;
                pv[p] = *(const uint4*)&Vt[vgl];
            }
        }

        // ---- S^T = K @ Q^T (split: Kh*Ql + Kl*Qh + Kh*Qh) ----
        f32x4 S[4];
#pragma unroll
        for (int kf = 0; kf < 4; kf++) S[kf] = (f32x4)(0.f);
        __builtin_amdgcn_s_setprio(1);
#pragma unroll
        for (int ds = 0; ds < 2; ds++) {
            short8 kh[4], kl[4];
#pragma unroll
            for (int kf = 0; kf < 4; kf++) {
                const int off = (kf * 16 + lr) * LP + ds * 32 + lg * 8;
                kh[kf] = *(const short8*)&Ks_hi[off];
                kl[kf] = *(const short8*)&Ks_lo[off];
            }
#pragma unroll
            for (int kf = 0; kf < 4; kf++) {
                S[kf] = __builtin_amdgcn_mfma_f32_16x16x32_bf16(
                    kh[kf], ql[ds], S[kf], 0, 0, 0);
                S[kf] = __builtin_amdgcn_mfma_f32_16x16x32_bf16(
                    kl[kf], qh[ds], S[kf], 0, 0, 0);
                S[kf] = __builtin_amdgcn_mfma_f32_16x16x32_bf16(
                    kh[kf], qh[ds], S[kf], 0, 0, 0);
            }
        }
        __builtin_amdgcn_s_setprio(0);

        // ---- causal mask (diagonal k-tile of the current phase) ----
        if (masked && t == qtcur) {
            const int qg = qtcur * 64 + w * 16 + lr;
#pragma unroll
            for (int kf = 0; kf < 4; kf++)
#pragma unroll
                for (int r = 0; r < 4; r++) {
                    const int kg = t * 64 + kf * 16 + 4 * lg + r;
                    if (kg > qg) S[kf][r] = -INFINITY;
                }
        }

        // ---- online softmax: in-reg over 16 + 2 shuffles across lg ----
        {
            float mt = -INFINITY;
#pragma unroll
            for (int kf = 0; kf < 4; kf++)
#pragma unroll
                for (int r = 0; r < 4; r++) mt = fmaxf(mt, S[kf][r]);
            mt = fmaxf(mt, __shfl_xor(mt, 16));
            mt = fmaxf(mt, __shfl_xor(mt, 32));
            const float mn = fmaxf(m_i, mt);
            const float corr = __expf(m_i - mn);
            float rs = 0.f;
#pragma unroll
            for (int kf = 0; kf < 4; kf++)
#pragma unroll
                for (int r = 0; r < 4; r++) {
                    const float p = __expf(S[kf][r] - mn);
                    S[kf][r] = p;
                    rs += p;
                }
            rs += __shfl_xor(rs, 16);
            rs += __shfl_xor(rs, 32);
            l_i = l_i * corr + rs;
            m_i = mn;
#pragma unroll
            for (int df = 0; df < 4; df++) Oacc[df] *= corr;
        }

        // ---- pack P: same-lane regs -> one b64 write per kf ----
#pragma unroll
        for (int kf = 0; kf < 4; kf++) {
            const unsigned int a = (unsigned int)f2bf(S[kf][0]) |
                                   ((unsigned int)f2bf(S[kf][1]) << 16);
            const unsigned int b = (unsigned int)f2bf(S[kf][2]) |
                                   ((unsigned int)f2bf(S[kf][3]) << 16);
            *(uint2*)&Ps[lr * PB + kf * 16 + 4 * lg] = make_uint2(a, b);
        }

        // ---- O^T += V^T @ P^T (per-wave private P, no barrier) ----
        __builtin_amdgcn_s_setprio(1);
#pragma unroll
        for (int ks = 0; ks < 2; ks++) {
            short8 vb[4];
#pragma unroll
            for (int df = 0; df < 4; df++)
                vb[df] = *(const short8*)&Vs[(df * 16 + lr) * LP + ks * 32 +
                                             lg * 8];
            const short8 pb = *(const short8*)&Ps[lr * PB + ks * 32 + lg * 8];
#pragma unroll
            for (int df = 0; df < 4; df++)
                Oacc[df] = __builtin_amdgcn_mfma_f32_16x16x32_bf16(
                    vb[df], pb, Oacc[df], 0, 0, 0);
        }
        __builtin_amdgcn_s_setprio(0);

        // ---- phase A done: write its O, reset, switch to tile B ----
        if (it == itersA - 1) {
            writeO(qa);
            resetState();
            loadQ(jj);
        }
        __syncthreads();  // protect K/V LDS for next iteration
    }

    writeO(jj);
}

// ===========================================================================
extern "C" void kernel_launch(void* const* d_in, const int* in_sizes, int n_in,
                              void* d_out, int out_size, void* d_ws,
                              size_t ws_size, hipStream_t stream) {
    const float* q  = (const float*)d_in[0];
    const float* k  = (const float*)d_in[1];
    const float* v  = (const float*)d_in[2];
    const float* Wq = (const float*)d_in[3];
    const float* Wk = (const float*)d_in[4];
    const float* Wv = (const float*)d_in[5];
    const float* Wo = (const float*)d_in[6];
    const int* masked = (const int*)d_in[7];

    float* out  = (float*)d_out;                 // [B,S,1024]
    float* attn = out + (size_t)CB * CS * CEMB;  // [B,H,S,64] (2nd output)

    // workspace layout (bf16 buffers, all 16B aligned):
    const size_t NE = (size_t)CB * CS * CEMB;  // 4M elems per tensor
    ushort_t* wsb = (ushort_t*)d_ws;
    ushort_t* Qhi = wsb + 0 * NE;
    ushort_t* Qlo = wsb + 1 * NE;
    ushort_t* Khi = wsb + 2 * NE;
    ushort_t* Klo = wsb + 3 * NE;
    ushort_t* Vt  = wsb + 4 * NE;   // [b,h,d,s]
    ushort_t* wb  = wsb + 5 * NE;   // split weights: 8 x 1M
    const size_t WN = (size_t)CEMB * CEMB;
    ushort_t* hq = wb + 0 * WN;  ushort_t* lq = wb + 1 * WN;
    ushort_t* hk = wb + 2 * WN;  ushort_t* lk = wb + 3 * WN;
    ushort_t* hv = wb + 4 * WN;  ushort_t* lv = wb + 5 * WN;
    ushort_t* ho = wb + 6 * WN;  ushort_t* lo_ = wb + 7 * WN;

    dim3 blk(256);

    convert_wt<<<dim3(16, 16, 4), blk, 0, stream>>>(
        Wq, Wk, Wv, Wo, hq, lq, hk, lk, hv, lv, ho, lo_);

    qkv_proj<<<dim3(768), blk, 0, stream>>>(
        q, k, v, hq, lq, hk, lk, hv, lv, Qhi, Qlo, Khi, Klo, Vt);

    flash_mfma<<<dim3(16, CB * CH), blk, 0, stream>>>(
        Qhi, Qlo, Khi, Klo, Vt, attn, masked);

    out_proj<<<dim3(256), blk, 0, stream>>>(attn, ho, lo_, out);
}